// Round 1
// baseline (221.311 us; speedup 1.0000x reference)
//
#include <hip/hip_runtime.h>

#define NT 512   // trajectories
#define PD 256   // dimension

__device__ __forceinline__ float wave_reduce_sum(float v) {
    #pragma unroll
    for (int m = 32; m >= 1; m >>= 1) v += __shfl_xor(v, m, 64);
    return v;
}

// Kernel 1: per trajectory n, compute two matvecs against predicted_mat:
//   qndg[n,p] = sum_q pm[n,p,q] * (grad[n,q] - gradm1[n,q])
//   pg[n,p]   = sum_q pm[n,p,q] * grad[n,q]
// One wave per row; lanes read float4 (coalesced 1 KiB per wave-load).
__global__ __launch_bounds__(256) void matvec2_kernel(
    const float* __restrict__ pm, const float* __restrict__ grad,
    const float* __restrict__ gradm1, float* __restrict__ qndg,
    float* __restrict__ pg)
{
    const int tid  = threadIdx.x;
    const int lane = tid & 63;
    const int wave = tid >> 6;
    const int n     = blockIdx.x >> 2;   // trajectory
    const int chunk = blockIdx.x & 3;    // which 64-row chunk

    const float4 g4  = ((const float4*)(grad   + n * PD))[lane];
    const float4 gm4 = ((const float4*)(gradm1 + n * PD))[lane];
    const float4 dg4 = make_float4(g4.x - gm4.x, g4.y - gm4.y,
                                   g4.z - gm4.z, g4.w - gm4.w);

    const int row0 = chunk * 64 + wave * 16;
    const float* base = pm + (size_t)n * PD * PD;
    #pragma unroll 4
    for (int r = 0; r < 16; ++r) {
        const int row = row0 + r;
        const float4 m4 = ((const float4*)(base + (size_t)row * PD))[lane];
        float aq = m4.x * dg4.x + m4.y * dg4.y + m4.z * dg4.z + m4.w * dg4.w;
        float ag = m4.x * g4.x  + m4.y * g4.y  + m4.z * g4.z  + m4.w * g4.w;
        aq = wave_reduce_sum(aq);
        ag = wave_reduce_sum(ag);
        if (lane == 0) {
            qndg[n * PD + row] = aq;
            pg[n * PD + row]   = ag;
        }
    }
}

// Kernel 2: one block per trajectory. Tiny MLPs per element, mean over P,
// rank-2 BFGS correction applied directly to v = -grad (new_mat never built).
__global__ __launch_bounds__(256) void epilogue_kernel(
    const float* __restrict__ qndg, const float* __restrict__ pgin,
    const float* __restrict__ grad, const float* __restrict__ gradm1,
    const float* __restrict__ dm1,
    const float* __restrict__ Wfs, const float* __restrict__ Wo1,
    const float* __restrict__ Wo2, const float* __restrict__ Wo3,
    const float* __restrict__ Wl1, const float* __restrict__ Wl2,
    const float* __restrict__ Wl3,
    float* __restrict__ dout)
{
    // weight layout in LDS: Wo1@0(18) Wo2@18(72) Wo3@90(36) Wl1@126(72)
    //                       Wl2@198(288) Wl3@486(24) Wfs@510(6)
    __shared__ float sW[516];
    __shared__ float redA[4][3];
    __shared__ float redB[4][4];

    const int tid  = threadIdx.x;
    const int lane = tid & 63;
    const int wave = tid >> 6;
    const int n    = blockIdx.x;

    if (tid < 18) sW[tid]       = Wo1[tid];
    if (tid < 72) sW[18 + tid]  = Wo2[tid];
    if (tid < 36) sW[90 + tid]  = Wo3[tid];
    if (tid < 72) sW[126 + tid] = Wl1[tid];
    sW[198 + tid] = Wl2[tid];                       // first 256 of 288
    if (tid < 32) sW[198 + 256 + tid] = Wl2[256 + tid];
    if (tid < 24) sW[486 + tid] = Wl3[tid];
    if (tid < 6)  sW[510 + tid] = Wfs[tid];
    __syncthreads();

    const int idx = n * PD + tid;
    const float q   = qndg[idx];
    const float bg  = -pgin[idx];   // Bg = -pm@grad = pm@v
    const float g   = grad[idx];
    const float gm  = gradm1[idx];
    const float dm  = dm1[idx];

    const float x0 = q, x1 = dm, x2 = bg;

    // outer_FF: 3 -> 6 -> 12 -> 3
    float h1[6];
    #pragma unroll
    for (int j = 0; j < 6; ++j) {
        float s = sW[j*3] * x0 + sW[j*3 + 1] * x1 + sW[j*3 + 2] * x2;
        h1[j] = fmaxf(s, 0.f);
    }
    float h2[12];
    #pragma unroll
    for (int j = 0; j < 12; ++j) {
        float s = 0.f;
        #pragma unroll
        for (int i = 0; i < 6; ++i) s += sW[18 + j*6 + i] * h1[i];
        h2[j] = fmaxf(s, 0.f);
    }
    float o0 = 0.f, o1 = 0.f, o2 = 0.f;
    #pragma unroll
    for (int i = 0; i < 12; ++i) {
        o0 += sW[90 + i]      * h2[i];
        o1 += sW[90 + 12 + i] * h2[i];
        o2 += sW[90 + 24 + i] * h2[i];
    }

    // mean over P (block reduction)
    float r0 = wave_reduce_sum(o0);
    float r1 = wave_reduce_sum(o1);
    float r2 = wave_reduce_sum(o2);
    if (lane == 0) { redA[wave][0] = r0; redA[wave][1] = r1; redA[wave][2] = r2; }
    __syncthreads();
    const float inv = 1.0f / 256.0f;
    const float of0 = (redA[0][0] + redA[1][0] + redA[2][0] + redA[3][0]) * inv;
    const float of1 = (redA[0][1] + redA[1][1] + redA[2][1] + redA[3][1]) * inv;
    const float of2 = (redA[0][2] + redA[1][2] + redA[2][2] + redA[3][2]) * inv;

    const float x6[6] = {x0, x1, x2, of0, of1, of2};

    float fullskip = 0.f;
    #pragma unroll
    for (int i = 0; i < 6; ++i) fullskip += sW[510 + i] * x6[i];

    // inner MLP: 6 -> 12 -> 24 -> 1
    float l1[12];
    #pragma unroll
    for (int j = 0; j < 12; ++j) {
        float s = 0.f;
        #pragma unroll
        for (int i = 0; i < 6; ++i) s += sW[126 + j*6 + i] * x6[i];
        l1[j] = fmaxf(s, 0.f);
    }
    float l2[24];
    #pragma unroll
    for (int j = 0; j < 24; ++j) {
        float s = 0.f;
        #pragma unroll
        for (int i = 0; i < 12; ++i) s += sW[198 + j*12 + i] * l1[i];
        l2[j] = fmaxf(s, 0.f);
    }
    float out = fullskip;
    #pragma unroll
    for (int i = 0; i < 24; ++i) out += sW[486 + i] * l2[i];

    const float dgk    = g - gm;
    const float secant = dm - q;

    // four simultaneous block reductions
    float pd  = wave_reduce_sum(out * dgk);
    float ps  = wave_reduce_sum(secant * dgk);
    float po  = wave_reduce_sum(out * g);
    float psg = wave_reduce_sum(secant * g);
    if (lane == 0) {
        redB[wave][0] = pd; redB[wave][1] = ps;
        redB[wave][2] = po; redB[wave][3] = psg;
    }
    __syncthreads();
    const float denom = redB[0][0] + redB[1][0] + redB[2][0] + redB[3][0];
    const float sdgk  = redB[0][1] + redB[1][1] + redB[2][1] + redB[3][1];
    const float og    = redB[0][2] + redB[1][2] + redB[2][2] + redB[3][2];  // sum(out*grad)
    const float sg    = redB[0][3] + redB[1][3] + redB[2][3] + redB[3][3];  // sum(secant*grad)

    // d = Bg + (1/denom)*( secant*(out.v) + out*(secant.v) - coef*out*(out.v) ),
    // v = -grad => out.v = -og, secant.v = -sg, coef = sdgk/denom
    const float invd = 1.0f / denom;
    const float coef = sdgk * invd;
    const float d = bg + (-secant * og - out * sg + coef * out * og) * invd;
    dout[idx] = d;
}

extern "C" void kernel_launch(void* const* d_in, const int* in_sizes, int n_in,
                              void* d_out, int out_size, void* d_ws, size_t ws_size,
                              hipStream_t stream) {
    const float* grad   = (const float*)d_in[0];
    const float* gradm1 = (const float*)d_in[1];
    const float* dm1    = (const float*)d_in[2];
    const float* pm     = (const float*)d_in[3];
    const float* Wfs    = (const float*)d_in[4];
    const float* Wo1    = (const float*)d_in[5];
    const float* Wo2    = (const float*)d_in[6];
    const float* Wo3    = (const float*)d_in[7];
    const float* Wl1    = (const float*)d_in[8];
    const float* Wl2    = (const float*)d_in[9];
    const float* Wl3    = (const float*)d_in[10];

    float* qndg = (float*)d_ws;            // N*P floats
    float* pgbuf = qndg + NT * PD;         // N*P floats

    matvec2_kernel<<<NT * 4, 256, 0, stream>>>(pm, grad, gradm1, qndg, pgbuf);
    epilogue_kernel<<<NT, 256, 0, stream>>>(qndg, pgbuf, grad, gradm1, dm1,
                                            Wfs, Wo1, Wo2, Wo3, Wl1, Wl2, Wl3,
                                            (float*)d_out);
}

// Round 2
// 216.534 us; speedup vs baseline: 1.0221x; 1.0221x over previous
//
#include <hip/hip_runtime.h>

#define NT 512     // trajectories
#define PD 256     // dimension
#define TROWS 32   // rows per LDS tile
#define NTILES 8   // PD / TROWS
#define LPITCH 257 // odd pitch: read banks (r + stuff) % 32 conflict-free

__device__ __forceinline__ float wave_reduce_sum(float v) {
    #pragma unroll
    for (int m = 32; m >= 1; m >>= 1) v += __shfl_xor(v, m, 64);
    return v;
}

// One block per trajectory. Phase 1: dual matvec vs predicted_mat via
// double-buffered LDS tiles, thread-per-row accumulation (no per-row
// cross-lane reductions). Phase 2: tiny-MLP epilogue + rank-2 BFGS update
// applied directly to v = -grad (new_mat never materialized).
__global__ __launch_bounds__(256) void fused_kernel(
    const float* __restrict__ pm, const float* __restrict__ grad,
    const float* __restrict__ gradm1, const float* __restrict__ dm1,
    const float* __restrict__ Wfs, const float* __restrict__ Wo1,
    const float* __restrict__ Wo2, const float* __restrict__ Wo3,
    const float* __restrict__ Wl1, const float* __restrict__ Wl2,
    const float* __restrict__ Wl3, float* __restrict__ dout)
{
    __shared__ float buf0[TROWS * LPITCH];   // 32.9 KB
    __shared__ float buf1[TROWS * LPITCH];   // 32.9 KB
    __shared__ float sW[516];
    __shared__ float redA[4][3];
    __shared__ float redB[4][4];

    const int t    = threadIdx.x;
    const int lane = t & 63;
    const int wave = t >> 6;
    const int n    = blockIdx.x;

    // ---- stage tiny weights (used in phase 2; barriers below cover it) ----
    if (t < 18) sW[t]       = Wo1[t];
    if (t < 72) sW[18 + t]  = Wo2[t];
    if (t < 36) sW[90 + t]  = Wo3[t];
    if (t < 72) sW[126 + t] = Wl1[t];
    sW[198 + t] = Wl2[t];
    if (t < 32) sW[198 + 256 + t] = Wl2[256 + t];
    if (t < 24) sW[486 + t] = Wl3[t];
    if (t < 6)  sW[510 + t] = Wfs[t];

    // ---- register-cache this thread's 32-column slice of grad / dgrad ----
    const int r  = t & 31;   // tile-local row this thread reduces
    const int cg = t >> 5;   // column group (8 groups of 32 columns)
    float gv[32], dgv[32];
    {
        const float4* gb  = (const float4*)(grad   + n * PD + cg * 32);
        const float4* gmb = (const float4*)(gradm1 + n * PD + cg * 32);
        #pragma unroll
        for (int i = 0; i < 8; ++i) {
            float4 a = gb[i];
            float4 b = gmb[i];
            gv[4*i+0] = a.x; gv[4*i+1] = a.y; gv[4*i+2] = a.z; gv[4*i+3] = a.w;
            dgv[4*i+0] = a.x - b.x; dgv[4*i+1] = a.y - b.y;
            dgv[4*i+2] = a.z - b.z; dgv[4*i+3] = a.w - b.w;
        }
    }

    const float* tbase = pm + (size_t)n * PD * PD;
    float4 stg[8];
    float accq[NTILES], accg[NTILES];

    // component-major layout: element (row, col) at row*LPITCH + (col&3)*64 + (col>>2)
    // staging wave handles whole rows: col = 4*lane + i -> offset i*64 + lane.

    // ---- prologue: load + write tile 0 ----
    #pragma unroll
    for (int j = 0; j < 8; ++j) {
        const int row = 4 * j + wave;
        stg[j] = ((const float4*)(tbase + (size_t)(0 * TROWS + row) * PD))[lane];
    }
    #pragma unroll
    for (int j = 0; j < 8; ++j) {
        const int row = 4 * j + wave;
        float* p = buf0 + row * LPITCH + lane;
        p[0] = stg[j].x; p[64] = stg[j].y; p[128] = stg[j].z; p[192] = stg[j].w;
    }
    __syncthreads();

    // ---- main double-buffered loop ----
    #pragma unroll
    for (int k = 0; k < NTILES; ++k) {
        if (k + 1 < NTILES) {
            #pragma unroll
            for (int j = 0; j < 8; ++j) {
                const int row = 4 * j + wave;
                stg[j] = ((const float4*)(tbase + (size_t)((k + 1) * TROWS + row) * PD))[lane];
            }
        }
        {   // compute partial dots for row r, columns [32*cg, 32*cg+32)
            const float* bp = ((k & 1) ? buf1 : buf0) + r * LPITCH + 8 * cg;
            float sq = 0.f, sg = 0.f;
            #pragma unroll
            for (int p = 0; p < 4; ++p) {
                #pragma unroll
                for (int q = 0; q < 8; ++q) {
                    const float m = bp[p * 64 + q];   // col = 32*cg + 4*q + p
                    sq += m * dgv[4*q + p];
                    sg += m * gv[4*q + p];
                }
            }
            accq[k] = sq; accg[k] = sg;
        }
        if (k + 1 < NTILES) {
            float* wb = ((k + 1) & 1) ? buf1 : buf0;
            #pragma unroll
            for (int j = 0; j < 8; ++j) {
                const int row = 4 * j + wave;
                float* p = wb + row * LPITCH + lane;
                p[0] = stg[j].x; p[64] = stg[j].y; p[128] = stg[j].z; p[192] = stg[j].w;
            }
        }
        __syncthreads();
    }

    // ---- combine partials: row p needs colgroups c=0..7 from threads (c<<5)|(p&31),
    //      tile k = p>>5. parts[k*256 + thread], aliased into buf0 (free now). ----
    float* partsQ = buf0;          // 2048 floats
    float* partsG = buf0 + 2048;   // 2048 floats
    #pragma unroll
    for (int k = 0; k < NTILES; ++k) {
        partsQ[k * 256 + t] = accq[k];
        partsG[k * 256 + t] = accg[k];
    }
    __syncthreads();

    float q = 0.f, pg = 0.f;
    {
        const int pb = (t >> 5) * 256 + (t & 31);
        #pragma unroll
        for (int c = 0; c < 8; ++c) {
            q  += partsQ[pb + 32 * c];
            pg += partsG[pb + 32 * c];
        }
    }

    // ---- phase 2: epilogue (validated in R1) ----
    const int idx = n * PD + t;
    const float bg = -pg;              // Bg = -pm@grad = pm@v
    const float g  = gv[t & 31];       // col 32*cg + (t&31) == t
    const float gm = g - dgv[t & 31];
    const float dm = dm1[idx];

    const float x0 = q, x1 = dm, x2 = bg;

    // outer_FF: 3 -> 6 -> 12 -> 3
    float h1[6];
    #pragma unroll
    for (int j = 0; j < 6; ++j) {
        float s = sW[j*3] * x0 + sW[j*3 + 1] * x1 + sW[j*3 + 2] * x2;
        h1[j] = fmaxf(s, 0.f);
    }
    float h2[12];
    #pragma unroll
    for (int j = 0; j < 12; ++j) {
        float s = 0.f;
        #pragma unroll
        for (int i = 0; i < 6; ++i) s += sW[18 + j*6 + i] * h1[i];
        h2[j] = fmaxf(s, 0.f);
    }
    float o0 = 0.f, o1 = 0.f, o2 = 0.f;
    #pragma unroll
    for (int i = 0; i < 12; ++i) {
        o0 += sW[90 + i]      * h2[i];
        o1 += sW[90 + 12 + i] * h2[i];
        o2 += sW[90 + 24 + i] * h2[i];
    }

    // mean over P (block reduction)
    float r0 = wave_reduce_sum(o0);
    float r1 = wave_reduce_sum(o1);
    float r2 = wave_reduce_sum(o2);
    if (lane == 0) { redA[wave][0] = r0; redA[wave][1] = r1; redA[wave][2] = r2; }
    __syncthreads();
    const float inv = 1.0f / 256.0f;
    const float of0 = (redA[0][0] + redA[1][0] + redA[2][0] + redA[3][0]) * inv;
    const float of1 = (redA[0][1] + redA[1][1] + redA[2][1] + redA[3][1]) * inv;
    const float of2 = (redA[0][2] + redA[1][2] + redA[2][2] + redA[3][2]) * inv;

    const float x6[6] = {x0, x1, x2, of0, of1, of2};

    float fullskip = 0.f;
    #pragma unroll
    for (int i = 0; i < 6; ++i) fullskip += sW[510 + i] * x6[i];

    // inner MLP: 6 -> 12 -> 24 -> 1
    float l1[12];
    #pragma unroll
    for (int j = 0; j < 12; ++j) {
        float s = 0.f;
        #pragma unroll
        for (int i = 0; i < 6; ++i) s += sW[126 + j*6 + i] * x6[i];
        l1[j] = fmaxf(s, 0.f);
    }
    float l2[24];
    #pragma unroll
    for (int j = 0; j < 24; ++j) {
        float s = 0.f;
        #pragma unroll
        for (int i = 0; i < 12; ++i) s += sW[198 + j*12 + i] * l1[i];
        l2[j] = fmaxf(s, 0.f);
    }
    float out = fullskip;
    #pragma unroll
    for (int i = 0; i < 24; ++i) out += sW[486 + i] * l2[i];

    const float dgk    = g - gm;
    const float secant = dm - q;

    // four simultaneous block reductions
    float pd  = wave_reduce_sum(out * dgk);
    float ps  = wave_reduce_sum(secant * dgk);
    float po  = wave_reduce_sum(out * g);
    float psg = wave_reduce_sum(secant * g);
    if (lane == 0) {
        redB[wave][0] = pd; redB[wave][1] = ps;
        redB[wave][2] = po; redB[wave][3] = psg;
    }
    __syncthreads();
    const float denom = redB[0][0] + redB[1][0] + redB[2][0] + redB[3][0];
    const float sdgk  = redB[0][1] + redB[1][1] + redB[2][1] + redB[3][1];
    const float og    = redB[0][2] + redB[1][2] + redB[2][2] + redB[3][2];
    const float sg2   = redB[0][3] + redB[1][3] + redB[2][3] + redB[3][3];

    // d = Bg + (1/denom)*( secant*(out.v) + out*(secant.v) - coef*out*(out.v) ),
    // v = -grad => out.v = -og, secant.v = -sg2, coef = sdgk/denom
    const float invd = 1.0f / denom;
    const float coef = sdgk * invd;
    const float d = bg + (-secant * og - out * sg2 + coef * out * og) * invd;
    dout[idx] = d;
}

extern "C" void kernel_launch(void* const* d_in, const int* in_sizes, int n_in,
                              void* d_out, int out_size, void* d_ws, size_t ws_size,
                              hipStream_t stream) {
    const float* grad   = (const float*)d_in[0];
    const float* gradm1 = (const float*)d_in[1];
    const float* dm1    = (const float*)d_in[2];
    const float* pm     = (const float*)d_in[3];
    const float* Wfs    = (const float*)d_in[4];
    const float* Wo1    = (const float*)d_in[5];
    const float* Wo2    = (const float*)d_in[6];
    const float* Wo3    = (const float*)d_in[7];
    const float* Wl1    = (const float*)d_in[8];
    const float* Wl2    = (const float*)d_in[9];
    const float* Wl3    = (const float*)d_in[10];

    fused_kernel<<<NT, 256, 0, stream>>>(pm, grad, gradm1, dm1,
                                         Wfs, Wo1, Wo2, Wo3, Wl1, Wl2, Wl3,
                                         (float*)d_out);
}